// Round 1
// baseline (782.369 us; speedup 1.0000x reference)
//
#include <hip/hip_runtime.h>
#include <hip/hip_bf16.h>
#include <math.h>

#define BATCH 16
#define SEQ   512
#define DC    1024
#define DP    64
#define NT    8
#define DH    4096
#define NTOK  (BATCH*SEQ)   // 8192

#define BM 128
#define BN 128
#define BK 32
#define KPAD 40             // BK + 8 pad: 80B rows keep 16B alignment, break bank stride

typedef __attribute__((ext_vector_type(8))) short short8;        // 8 bf16 (4 VGPRs)
typedef __attribute__((ext_vector_type(4))) float floatx4;       // MFMA acc
typedef __attribute__((ext_vector_type(4))) unsigned short ushort4v;

__device__ inline unsigned short f2bf(float f) {
  union { float f; unsigned u; } v; v.f = f;
  unsigned r = v.u + 0x7FFFu + ((v.u >> 16) & 1u);   // round-to-nearest-even
  return (unsigned short)(r >> 16);
}

// ---------------- routing: one wave per token ----------------
__global__ __launch_bounds__(256) void route_kernel(
    const float* __restrict__ x, const float* __restrict__ pe,
    const float* __restrict__ pwp, const float* __restrict__ cwp,
    const float* __restrict__ pos_sigs, const float* __restrict__ csigs,
    int* __restrict__ counts, int* __restrict__ list,
    unsigned short* __restrict__ xb) {
  int wid  = threadIdx.x >> 6;
  int lane = threadIdx.x & 63;
  int token = blockIdx.x * 4 + wid;          // grid = NTOK/4, always in range
  int s = token & (SEQ - 1);

  float pwr = 1.f / (1.f + expf(-pwp[0]));
  float cwr = 1.f / (1.f + expf(-cwp[0]));
  float tot = pwr + cwr;
  float pw = pwr / tot, cw = cwr / tot;

  float acc[NT];
#pragma unroll
  for (int t = 0; t < NT; t++) acc[t] = 0.f;

  // position part: dims 0..63 == lane
  float a0 = pw * pe[s * DP + lane];
#pragma unroll
  for (int t = 0; t < NT; t++) {
    float v = pos_sigs[t * DP + lane];
    float sg = (v > 0.f) ? 1.f : ((v < 0.f) ? -1.f : 0.f);
    acc[t] = fmaf(a0, sg, acc[t]);
  }

  // content part + bf16 conversion of x into ws
  const float* xrow = x + (size_t)token * DC;
  unsigned short* xbrow = xb + (size_t)token * DC;
#pragma unroll 4
  for (int i = 0; i < DC / 64; i++) {
    int c = lane + i * 64;
    float xv = xrow[c];
    xbrow[c] = f2bf(xv);
    float a = cw * xv;
#pragma unroll
    for (int t = 0; t < NT; t++) {
      float v = csigs[t * DC + c];
      float sg = (v > 0.f) ? 1.f : ((v < 0.f) ? -1.f : 0.f);
      acc[t] = fmaf(a, sg, acc[t]);
    }
  }

  // butterfly reduce across the 64-lane wave
#pragma unroll
  for (int off = 32; off >= 1; off >>= 1)
#pragma unroll
    for (int t = 0; t < NT; t++) acc[t] += __shfl_xor(acc[t], off);

  if (lane == 0) {
    int best = 0; float bv = acc[0];
#pragma unroll
    for (int t = 1; t < NT; t++)
      if (acc[t] > bv) { bv = acc[t]; best = t; }   // first-max, like jnp.argmax
    int slot = atomicAdd(&counts[best], 1);
    list[best * NTOK + slot] = token;
  }
}

// ---------------- GEMM1: H = gelu(Xg * W1[t] + b1[t]) ----------------
__global__ __launch_bounds__(256) void gemm1_kernel(
    const unsigned short* __restrict__ xb, const float* __restrict__ W1,
    const float* __restrict__ b1, const int* __restrict__ counts,
    const int* __restrict__ list, unsigned short* __restrict__ H) {
  int t = blockIdx.z;
  int count = counts[t];
  int base = blockIdx.y * BM;
  if (base >= count) return;
  int j0 = blockIdx.x * BN;

  __shared__ unsigned short As[BM][KPAD];
  __shared__ unsigned short Bs[BN][KPAD];
  __shared__ int toks[BM];

  int tid = threadIdx.x;
  if (tid < BM) {
    int slot = base + tid;
    toks[tid] = (slot < count) ? list[t * NTOK + slot] : -1;
  }
  __syncthreads();

  int arow = tid >> 1;
  int acol = (tid & 1) * 16;
  int mytok = toks[arow];
  const unsigned short* xrow = xb + (size_t)(mytok < 0 ? 0 : mytok) * DC;

  int kg4 = (tid >> 5) * 4;   // k sub-block 0,4,..28
  int ng4 = (tid & 31) * 4;   // n sub-block 0,4,..124
  const float* Wt = W1 + (size_t)t * DC * DH;

  int wid = tid >> 6, lane = tid & 63;
  int wm = (wid & 1) * 64, wn = (wid >> 1) * 64;
  int quad = lane >> 4, l15 = lane & 15;

  floatx4 acc[4][4];
#pragma unroll
  for (int mi = 0; mi < 4; mi++)
#pragma unroll
    for (int ni = 0; ni < 4; ni++) acc[mi][ni] = (floatx4){0.f, 0.f, 0.f, 0.f};

  for (int kt = 0; kt < DC / BK; kt++) {
    int k0 = kt * BK;
    // stage A (gathered bf16 rows): 16 elems/thread as two 16B copies
    if (mytok >= 0) {
      uint4 v0 = *(const uint4*)(xrow + k0 + acol);
      uint4 v1 = *(const uint4*)(xrow + k0 + acol + 8);
      *(uint4*)&As[arow][acol]     = v0;
      *(uint4*)&As[arow][acol + 8] = v1;
    } else {
      uint4 z = {0u, 0u, 0u, 0u};
      *(uint4*)&As[arow][acol]     = z;
      *(uint4*)&As[arow][acol + 8] = z;
    }
    // stage B transposed: 4x4 micro-transpose, fp32 -> bf16
    const float* wb = Wt + (size_t)(k0 + kg4) * DH + j0 + ng4;
    float4 r0 = *(const float4*)(wb);
    float4 r1 = *(const float4*)(wb + DH);
    float4 r2 = *(const float4*)(wb + 2 * DH);
    float4 r3 = *(const float4*)(wb + 3 * DH);
    ushort4v c0 = { f2bf(r0.x), f2bf(r1.x), f2bf(r2.x), f2bf(r3.x) };
    ushort4v c1 = { f2bf(r0.y), f2bf(r1.y), f2bf(r2.y), f2bf(r3.y) };
    ushort4v c2 = { f2bf(r0.z), f2bf(r1.z), f2bf(r2.z), f2bf(r3.z) };
    ushort4v c3 = { f2bf(r0.w), f2bf(r1.w), f2bf(r2.w), f2bf(r3.w) };
    *(ushort4v*)&Bs[ng4 + 0][kg4] = c0;
    *(ushort4v*)&Bs[ng4 + 1][kg4] = c1;
    *(ushort4v*)&Bs[ng4 + 2][kg4] = c2;
    *(ushort4v*)&Bs[ng4 + 3][kg4] = c3;
    __syncthreads();

    short8 a[4], b[4];
#pragma unroll
    for (int mi = 0; mi < 4; mi++)
      a[mi] = *(const short8*)&As[wm + mi * 16 + l15][quad * 8];
#pragma unroll
    for (int ni = 0; ni < 4; ni++)
      b[ni] = *(const short8*)&Bs[wn + ni * 16 + l15][quad * 8];
#pragma unroll
    for (int mi = 0; mi < 4; mi++)
#pragma unroll
      for (int ni = 0; ni < 4; ni++)
        acc[mi][ni] = __builtin_amdgcn_mfma_f32_16x16x32_bf16(a[mi], b[ni], acc[mi][ni], 0, 0, 0);
    __syncthreads();
  }

  // epilogue: bias + exact gelu -> H (bf16), scatter by token
#pragma unroll
  for (int ni = 0; ni < 4; ni++) {
    int n = j0 + wn + ni * 16 + l15;
    float bias = b1[t * DH + n];
#pragma unroll
    for (int mi = 0; mi < 4; mi++) {
      int mb = wm + mi * 16 + quad * 4;
#pragma unroll
      for (int r = 0; r < 4; r++) {
        int tok = toks[mb + r];
        if (tok >= 0) {
          float v = acc[mi][ni][r] + bias;
          v = 0.5f * v * (1.f + erff(v * 0.70710678118654752f));
          H[(size_t)tok * DH + n] = f2bf(v);
        }
      }
    }
  }
}

// ---------------- GEMM2: out = Hg * W2[t] + b2[t] ----------------
__global__ __launch_bounds__(256) void gemm2_kernel(
    const unsigned short* __restrict__ H, const float* __restrict__ W2,
    const float* __restrict__ b2, const int* __restrict__ counts,
    const int* __restrict__ list, float* __restrict__ out) {
  int t = blockIdx.z;
  int count = counts[t];
  int base = blockIdx.y * BM;
  if (base >= count) return;
  int j0 = blockIdx.x * BN;

  __shared__ unsigned short As[BM][KPAD];
  __shared__ unsigned short Bs[BN][KPAD];
  __shared__ int toks[BM];

  int tid = threadIdx.x;
  if (tid < BM) {
    int slot = base + tid;
    toks[tid] = (slot < count) ? list[t * NTOK + slot] : -1;
  }
  __syncthreads();

  int arow = tid >> 1;
  int acol = (tid & 1) * 16;
  int mytok = toks[arow];
  const unsigned short* hrow = H + (size_t)(mytok < 0 ? 0 : mytok) * DH;

  int kg4 = (tid >> 5) * 4;
  int ng4 = (tid & 31) * 4;
  const float* Wt = W2 + (size_t)t * DH * DC;

  int wid = tid >> 6, lane = tid & 63;
  int wm = (wid & 1) * 64, wn = (wid >> 1) * 64;
  int quad = lane >> 4, l15 = lane & 15;

  floatx4 acc[4][4];
#pragma unroll
  for (int mi = 0; mi < 4; mi++)
#pragma unroll
    for (int ni = 0; ni < 4; ni++) acc[mi][ni] = (floatx4){0.f, 0.f, 0.f, 0.f};

  for (int kt = 0; kt < DH / BK; kt++) {
    int k0 = kt * BK;
    if (mytok >= 0) {
      uint4 v0 = *(const uint4*)(hrow + k0 + acol);
      uint4 v1 = *(const uint4*)(hrow + k0 + acol + 8);
      *(uint4*)&As[arow][acol]     = v0;
      *(uint4*)&As[arow][acol + 8] = v1;
    } else {
      uint4 z = {0u, 0u, 0u, 0u};
      *(uint4*)&As[arow][acol]     = z;
      *(uint4*)&As[arow][acol + 8] = z;
    }
    const float* wb = Wt + (size_t)(k0 + kg4) * DC + j0 + ng4;
    float4 r0 = *(const float4*)(wb);
    float4 r1 = *(const float4*)(wb + DC);
    float4 r2 = *(const float4*)(wb + 2 * DC);
    float4 r3 = *(const float4*)(wb + 3 * DC);
    ushort4v c0 = { f2bf(r0.x), f2bf(r1.x), f2bf(r2.x), f2bf(r3.x) };
    ushort4v c1 = { f2bf(r0.y), f2bf(r1.y), f2bf(r2.y), f2bf(r3.y) };
    ushort4v c2 = { f2bf(r0.z), f2bf(r1.z), f2bf(r2.z), f2bf(r3.z) };
    ushort4v c3 = { f2bf(r0.w), f2bf(r1.w), f2bf(r2.w), f2bf(r3.w) };
    *(ushort4v*)&Bs[ng4 + 0][kg4] = c0;
    *(ushort4v*)&Bs[ng4 + 1][kg4] = c1;
    *(ushort4v*)&Bs[ng4 + 2][kg4] = c2;
    *(ushort4v*)&Bs[ng4 + 3][kg4] = c3;
    __syncthreads();

    short8 a[4], b[4];
#pragma unroll
    for (int mi = 0; mi < 4; mi++)
      a[mi] = *(const short8*)&As[wm + mi * 16 + l15][quad * 8];
#pragma unroll
    for (int ni = 0; ni < 4; ni++)
      b[ni] = *(const short8*)&Bs[wn + ni * 16 + l15][quad * 8];
#pragma unroll
    for (int mi = 0; mi < 4; mi++)
#pragma unroll
      for (int ni = 0; ni < 4; ni++)
        acc[mi][ni] = __builtin_amdgcn_mfma_f32_16x16x32_bf16(a[mi], b[ni], acc[mi][ni], 0, 0, 0);
    __syncthreads();
  }

#pragma unroll
  for (int ni = 0; ni < 4; ni++) {
    int n = j0 + wn + ni * 16 + l15;
    float bias = b2[t * DC + n];
#pragma unroll
    for (int mi = 0; mi < 4; mi++) {
      int mb = wm + mi * 16 + quad * 4;
#pragma unroll
      for (int r = 0; r < 4; r++) {
        int tok = toks[mb + r];
        if (tok >= 0) {
          out[(size_t)tok * DC + n] = acc[mi][ni][r] + bias;
        }
      }
    }
  }
}

extern "C" void kernel_launch(void* const* d_in, const int* in_sizes, int n_in,
                              void* d_out, int out_size, void* d_ws, size_t ws_size,
                              hipStream_t stream) {
  const float* x        = (const float*)d_in[0];
  const float* pe       = (const float*)d_in[1];
  const float* pwp      = (const float*)d_in[2];
  const float* cwp      = (const float*)d_in[3];
  const float* pos_sigs = (const float*)d_in[4];
  const float* csigs    = (const float*)d_in[5];
  const float* W1       = (const float*)d_in[6];
  const float* b1       = (const float*)d_in[7];
  const float* W2       = (const float*)d_in[8];
  const float* b2       = (const float*)d_in[9];
  float* out = (float*)d_out;

  char* ws = (char*)d_ws;
  int* counts        = (int*)ws;                                  // 32 B
  int* list          = (int*)(ws + 1024);                         // 256 KB
  unsigned short* xb = (unsigned short*)(ws + (1 << 20));         // 16 MB
  unsigned short* H  = (unsigned short*)(ws + ((size_t)32 << 20));// 64 MB
  // total ws footprint: 96 MB

  hipMemsetAsync(counts, 0, NT * sizeof(int), stream);
  route_kernel<<<NTOK / 4, 256, 0, stream>>>(x, pe, pwp, cwp, pos_sigs, csigs,
                                             counts, list, xb);
  gemm1_kernel<<<dim3(DH / BN, NTOK / BM, NT), 256, 0, stream>>>(xb, W1, b1, counts, list, H);
  gemm2_kernel<<<dim3(DC / BN, NTOK / BM, NT), 256, 0, stream>>>(H, W2, b2, counts, list, out);
}

// Round 2
// 706.554 us; speedup vs baseline: 1.1073x; 1.1073x over previous
//
#include <hip/hip_runtime.h>
#include <hip/hip_bf16.h>
#include <math.h>

#define BATCH 16
#define SEQ   512
#define DC    1024
#define DP    64
#define NT    8
#define DH    4096
#define NTOK  (BATCH*SEQ)   // 8192

#define BM 128
#define BN 128
#define BK 32

typedef __attribute__((ext_vector_type(8))) short short8;        // 8 bf16
typedef __attribute__((ext_vector_type(4))) float floatx4;       // MFMA acc
typedef __attribute__((ext_vector_type(4))) unsigned short ushort4v;
typedef __attribute__((ext_vector_type(8))) unsigned short ushort8v;

__device__ __forceinline__ unsigned short f2bf(float f) {
  union { float f; unsigned u; } v; v.f = f;
  unsigned r = v.u + 0x7FFFu + ((v.u >> 16) & 1u);   // round-to-nearest-even
  return (unsigned short)(r >> 16);
}

// async global -> LDS, 16B per lane, LDS dst = uniform base + lane*16
__device__ __forceinline__ void gl_lds16(const void* g, void* l) {
  __builtin_amdgcn_global_load_lds(
      (__attribute__((address_space(1))) void*)g,
      (__attribute__((address_space(3))) void*)l, 16, 0, 0);
}

// ---------------- routing: one wave per token (also writes bf16 copy of x) ----
__global__ __launch_bounds__(256) void route_kernel(
    const float* __restrict__ x, const float* __restrict__ pe,
    const float* __restrict__ pwp, const float* __restrict__ cwp,
    const float* __restrict__ pos_sigs, const float* __restrict__ csigs,
    int* __restrict__ counts, int* __restrict__ list,
    unsigned short* __restrict__ xb) {
  int wid  = threadIdx.x >> 6;
  int lane = threadIdx.x & 63;
  int token = blockIdx.x * 4 + wid;
  int s = token & (SEQ - 1);

  float pwr = 1.f / (1.f + expf(-pwp[0]));
  float cwr = 1.f / (1.f + expf(-cwp[0]));
  float tot = pwr + cwr;
  float pw = pwr / tot, cw = cwr / tot;

  float acc[NT];
#pragma unroll
  for (int t = 0; t < NT; t++) acc[t] = 0.f;

  float a0 = pw * pe[s * DP + lane];
#pragma unroll
  for (int t = 0; t < NT; t++) {
    float v = pos_sigs[t * DP + lane];
    float sg = (v > 0.f) ? 1.f : ((v < 0.f) ? -1.f : 0.f);
    acc[t] = fmaf(a0, sg, acc[t]);
  }

  const float* xrow = x + (size_t)token * DC;
  unsigned short* xbrow = xb + (size_t)token * DC;
#pragma unroll 4
  for (int i = 0; i < DC / 64; i++) {
    int c = lane + i * 64;
    float xv = xrow[c];
    xbrow[c] = f2bf(xv);
    float a = cw * xv;
#pragma unroll
    for (int t = 0; t < NT; t++) {
      float v = csigs[t * DC + c];
      float sg = (v > 0.f) ? 1.f : ((v < 0.f) ? -1.f : 0.f);
      acc[t] = fmaf(a, sg, acc[t]);
    }
  }

#pragma unroll
  for (int off = 32; off >= 1; off >>= 1)
#pragma unroll
    for (int t = 0; t < NT; t++) acc[t] += __shfl_xor(acc[t], off);

  if (lane == 0) {
    int best = 0; float bv = acc[0];
#pragma unroll
    for (int t = 1; t < NT; t++)
      if (acc[t] > bv) { bv = acc[t]; best = t; }
    int slot = atomicAdd(&counts[best], 1);
    list[best * NTOK + slot] = token;
  }
}

// ------------- transpose+convert: in [AR][AC] fp32 -> out [AC][AR] bf16 ------
template<int AR, int AC>
__global__ __launch_bounds__(256) void transpose_kernel(
    const float* __restrict__ in, unsigned short* __restrict__ out) {
  __shared__ unsigned short tile[64 * 65];
  int t = blockIdx.z;
  const float* in_t = in + (size_t)t * AR * AC;
  unsigned short* out_t = out + (size_t)t * AR * AC;
  int x0 = blockIdx.x * 64, y0 = blockIdx.y * 64;
  int tid = threadIdx.x;
  int ry = tid >> 2, cx = (tid & 3) * 16;
  const float* src = in_t + (size_t)(y0 + ry) * AC + x0 + cx;
  float4 v0 = *(const float4*)(src);
  float4 v1 = *(const float4*)(src + 4);
  float4 v2 = *(const float4*)(src + 8);
  float4 v3 = *(const float4*)(src + 12);
  unsigned short* trow = &tile[ry * 65 + cx];
  trow[0]  = f2bf(v0.x); trow[1]  = f2bf(v0.y); trow[2]  = f2bf(v0.z); trow[3]  = f2bf(v0.w);
  trow[4]  = f2bf(v1.x); trow[5]  = f2bf(v1.y); trow[6]  = f2bf(v1.z); trow[7]  = f2bf(v1.w);
  trow[8]  = f2bf(v2.x); trow[9]  = f2bf(v2.y); trow[10] = f2bf(v2.z); trow[11] = f2bf(v2.w);
  trow[12] = f2bf(v3.x); trow[13] = f2bf(v3.y); trow[14] = f2bf(v3.z); trow[15] = f2bf(v3.w);
  __syncthreads();
  int rx = tid >> 2, cy = (tid & 3) * 16;
  ushort8v o0, o1;
#pragma unroll
  for (int j = 0; j < 8; j++) o0[j] = tile[(cy + j) * 65 + rx];
#pragma unroll
  for (int j = 0; j < 8; j++) o1[j] = tile[(cy + 8 + j) * 65 + rx];
  size_t ob = (size_t)(x0 + rx) * AR + y0 + cy;
  *(ushort8v*)&out_t[ob]     = o0;
  *(ushort8v*)&out_t[ob + 8] = o1;
}

// ---------------- m97-style gathered GEMM, async LDS staging ----------------
// A: [NTOK][K] bf16 gathered via list; BT: [NT][N][K] bf16; C: bias + (gelu)
template<int K, int N, bool GELU>
__global__ __launch_bounds__(256) void gemm_async_kernel(
    const unsigned short* __restrict__ A, const unsigned short* __restrict__ BT,
    const float* __restrict__ bias, const int* __restrict__ counts,
    const int* __restrict__ list, unsigned short* __restrict__ Hout,
    float* __restrict__ Fout) {
  int t = blockIdx.z;
  int count = counts[t];
  int base = blockIdx.y * BM;
  if (base >= count) return;
  int j0 = blockIdx.x * BN;

  __shared__ unsigned short As[BM * BK];   // 8 KB, row-major [128][32], XOR-swizzled chunks
  __shared__ unsigned short Bs[BN * BK];   // 8 KB
  __shared__ int toks[BM];

  int tid = threadIdx.x;
  if (tid < BM) {
    int slot = base + tid;
    toks[tid] = (slot < count) ? list[t * NTOK + slot] : -1;
  }
  __syncthreads();

  int w = tid >> 6, lane = tid & 63;
  int lrow = lane >> 2;                    // 0..15 within 16-row chunk
  int lc   = lane & 3;                     // physical 16B chunk within row
  int swz  = (lc ^ (lrow & 3)) * 8;        // source k-offset (ushorts) for XOR swizzle

  const unsigned short* srcA[2];
  const unsigned short* srcB[2];
  unsigned short* dstA[2];
  unsigned short* dstB[2];
#pragma unroll
  for (int i = 0; i < 2; i++) {
    int ch = i * 4 + w;                    // 16-row chunk id, wave-uniform
    int r = ch * 16 + lrow;
    int tk = toks[r]; if (tk < 0) tk = 0;  // garbage rows computed, never written
    srcA[i] = A + (size_t)tk * K + swz;
    srcB[i] = BT + (size_t)t * N * K + (size_t)(j0 + r) * K + swz;
    dstA[i] = &As[ch * 512];
    dstB[i] = &Bs[ch * 512];
  }

  int wm = (w & 1) * 64, wn = (w >> 1) * 64;
  int quad = lane >> 4, l15 = lane & 15;
  int fswz = (quad ^ (l15 & 3)) * 8;       // physical chunk holding k-chunk `quad`

  floatx4 acc[4][4];
#pragma unroll
  for (int mi = 0; mi < 4; mi++)
#pragma unroll
    for (int ni = 0; ni < 4; ni++) acc[mi][ni] = (floatx4){0.f, 0.f, 0.f, 0.f};

  for (int k0 = 0; k0 < K; k0 += BK) {
#pragma unroll
    for (int i = 0; i < 2; i++) {
      gl_lds16(srcA[i], dstA[i]);
      gl_lds16(srcB[i], dstB[i]);
      srcA[i] += BK; srcB[i] += BK;
    }
    __syncthreads();

    short8 a[4], b[4];
#pragma unroll
    for (int mi = 0; mi < 4; mi++)
      a[mi] = *(const short8*)&As[(wm + mi * 16 + l15) * BK + fswz];
#pragma unroll
    for (int ni = 0; ni < 4; ni++)
      b[ni] = *(const short8*)&Bs[(wn + ni * 16 + l15) * BK + fswz];
#pragma unroll
    for (int mi = 0; mi < 4; mi++)
#pragma unroll
      for (int ni = 0; ni < 4; ni++)
        acc[mi][ni] = __builtin_amdgcn_mfma_f32_16x16x32_bf16(a[mi], b[ni], acc[mi][ni], 0, 0, 0);
    __syncthreads();
  }

#pragma unroll
  for (int ni = 0; ni < 4; ni++) {
    int n = j0 + wn + ni * 16 + l15;
    float bv = bias[t * N + n];
#pragma unroll
    for (int mi = 0; mi < 4; mi++) {
      int mb = wm + mi * 16 + quad * 4;
#pragma unroll
      for (int r = 0; r < 4; r++) {
        int tok = toks[mb + r];
        if (tok >= 0) {
          float v = acc[mi][ni][r] + bv;
          if (GELU) {
            v = 0.5f * v * (1.f + erff(v * 0.70710678118654752f));
            Hout[(size_t)tok * N + n] = f2bf(v);
          } else {
            Fout[(size_t)tok * N + n] = v;
          }
        }
      }
    }
  }
}

// ================= fallback (round-1 kernels, used if ws too small) ==========
#define KPAD 40
__global__ __launch_bounds__(256) void gemm1_fb(
    const unsigned short* __restrict__ xb, const float* __restrict__ W1,
    const float* __restrict__ b1, const int* __restrict__ counts,
    const int* __restrict__ list, unsigned short* __restrict__ H) {
  int t = blockIdx.z;
  int count = counts[t];
  int base = blockIdx.y * BM;
  if (base >= count) return;
  int j0 = blockIdx.x * BN;
  __shared__ unsigned short As[BM][KPAD];
  __shared__ unsigned short Bs[BN][KPAD];
  __shared__ int toks[BM];
  int tid = threadIdx.x;
  if (tid < BM) {
    int slot = base + tid;
    toks[tid] = (slot < count) ? list[t * NTOK + slot] : -1;
  }
  __syncthreads();
  int arow = tid >> 1, acol = (tid & 1) * 16;
  int mytok = toks[arow];
  const unsigned short* xrow = xb + (size_t)(mytok < 0 ? 0 : mytok) * DC;
  int kg4 = (tid >> 5) * 4, ng4 = (tid & 31) * 4;
  const float* Wt = W1 + (size_t)t * DC * DH;
  int wid = tid >> 6, lane = tid & 63;
  int wm = (wid & 1) * 64, wn = (wid >> 1) * 64;
  int quad = lane >> 4, l15 = lane & 15;
  floatx4 acc[4][4];
#pragma unroll
  for (int mi = 0; mi < 4; mi++)
#pragma unroll
    for (int ni = 0; ni < 4; ni++) acc[mi][ni] = (floatx4){0.f, 0.f, 0.f, 0.f};
  for (int kt = 0; kt < DC / BK; kt++) {
    int k0 = kt * BK;
    if (mytok >= 0) {
      *(uint4*)&As[arow][acol]     = *(const uint4*)(xrow + k0 + acol);
      *(uint4*)&As[arow][acol + 8] = *(const uint4*)(xrow + k0 + acol + 8);
    } else {
      uint4 z = {0u,0u,0u,0u};
      *(uint4*)&As[arow][acol] = z; *(uint4*)&As[arow][acol + 8] = z;
    }
    const float* wb = Wt + (size_t)(k0 + kg4) * DH + j0 + ng4;
    float4 r0 = *(const float4*)(wb);
    float4 r1 = *(const float4*)(wb + DH);
    float4 r2 = *(const float4*)(wb + 2 * DH);
    float4 r3 = *(const float4*)(wb + 3 * DH);
    ushort4v c0 = { f2bf(r0.x), f2bf(r1.x), f2bf(r2.x), f2bf(r3.x) };
    ushort4v c1 = { f2bf(r0.y), f2bf(r1.y), f2bf(r2.y), f2bf(r3.y) };
    ushort4v c2 = { f2bf(r0.z), f2bf(r1.z), f2bf(r2.z), f2bf(r3.z) };
    ushort4v c3 = { f2bf(r0.w), f2bf(r1.w), f2bf(r2.w), f2bf(r3.w) };
    *(ushort4v*)&Bs[ng4 + 0][kg4] = c0; *(ushort4v*)&Bs[ng4 + 1][kg4] = c1;
    *(ushort4v*)&Bs[ng4 + 2][kg4] = c2; *(ushort4v*)&Bs[ng4 + 3][kg4] = c3;
    __syncthreads();
    short8 a[4], b[4];
#pragma unroll
    for (int mi = 0; mi < 4; mi++) a[mi] = *(const short8*)&As[wm + mi * 16 + l15][quad * 8];
#pragma unroll
    for (int ni = 0; ni < 4; ni++) b[ni] = *(const short8*)&Bs[wn + ni * 16 + l15][quad * 8];
#pragma unroll
    for (int mi = 0; mi < 4; mi++)
#pragma unroll
      for (int ni = 0; ni < 4; ni++)
        acc[mi][ni] = __builtin_amdgcn_mfma_f32_16x16x32_bf16(a[mi], b[ni], acc[mi][ni], 0, 0, 0);
    __syncthreads();
  }
#pragma unroll
  for (int ni = 0; ni < 4; ni++) {
    int n = j0 + wn + ni * 16 + l15;
    float bias = b1[t * DH + n];
#pragma unroll
    for (int mi = 0; mi < 4; mi++) {
      int mb = wm + mi * 16 + quad * 4;
#pragma unroll
      for (int r = 0; r < 4; r++) {
        int tok = toks[mb + r];
        if (tok >= 0) {
          float v = acc[mi][ni][r] + bias;
          v = 0.5f * v * (1.f + erff(v * 0.70710678118654752f));
          H[(size_t)tok * DH + n] = f2bf(v);
        }
      }
    }
  }
}

__global__ __launch_bounds__(256) void gemm2_fb(
    const unsigned short* __restrict__ H, const float* __restrict__ W2,
    const float* __restrict__ b2, const int* __restrict__ counts,
    const int* __restrict__ list, float* __restrict__ out) {
  int t = blockIdx.z;
  int count = counts[t];
  int base = blockIdx.y * BM;
  if (base >= count) return;
  int j0 = blockIdx.x * BN;
  __shared__ unsigned short As[BM][KPAD];
  __shared__ unsigned short Bs[BN][KPAD];
  __shared__ int toks[BM];
  int tid = threadIdx.x;
  if (tid < BM) {
    int slot = base + tid;
    toks[tid] = (slot < count) ? list[t * NTOK + slot] : -1;
  }
  __syncthreads();
  int arow = tid >> 1, acol = (tid & 1) * 16;
  int mytok = toks[arow];
  const unsigned short* hrow = H + (size_t)(mytok < 0 ? 0 : mytok) * DH;
  int kg4 = (tid >> 5) * 4, ng4 = (tid & 31) * 4;
  const float* Wt = W2 + (size_t)t * DH * DC;
  int wid = tid >> 6, lane = tid & 63;
  int wm = (wid & 1) * 64, wn = (wid >> 1) * 64;
  int quad = lane >> 4, l15 = lane & 15;
  floatx4 acc[4][4];
#pragma unroll
  for (int mi = 0; mi < 4; mi++)
#pragma unroll
    for (int ni = 0; ni < 4; ni++) acc[mi][ni] = (floatx4){0.f, 0.f, 0.f, 0.f};
  for (int kt = 0; kt < DH / BK; kt++) {
    int k0 = kt * BK;
    if (mytok >= 0) {
      *(uint4*)&As[arow][acol]     = *(const uint4*)(hrow + k0 + acol);
      *(uint4*)&As[arow][acol + 8] = *(const uint4*)(hrow + k0 + acol + 8);
    } else {
      uint4 z = {0u,0u,0u,0u};
      *(uint4*)&As[arow][acol] = z; *(uint4*)&As[arow][acol + 8] = z;
    }
    const float* wb = Wt + (size_t)(k0 + kg4) * DC + j0 + ng4;
    float4 r0 = *(const float4*)(wb);
    float4 r1 = *(const float4*)(wb + DC);
    float4 r2 = *(const float4*)(wb + 2 * DC);
    float4 r3 = *(const float4*)(wb + 3 * DC);
    ushort4v c0 = { f2bf(r0.x), f2bf(r1.x), f2bf(r2.x), f2bf(r3.x) };
    ushort4v c1 = { f2bf(r0.y), f2bf(r1.y), f2bf(r2.y), f2bf(r3.y) };
    ushort4v c2 = { f2bf(r0.z), f2bf(r1.z), f2bf(r2.z), f2bf(r3.z) };
    ushort4v c3 = { f2bf(r0.w), f2bf(r1.w), f2bf(r2.w), f2bf(r3.w) };
    *(ushort4v*)&Bs[ng4 + 0][kg4] = c0; *(ushort4v*)&Bs[ng4 + 1][kg4] = c1;
    *(ushort4v*)&Bs[ng4 + 2][kg4] = c2; *(ushort4v*)&Bs[ng4 + 3][kg4] = c3;
    __syncthreads();
    short8 a[4], b[4];
#pragma unroll
    for (int mi = 0; mi < 4; mi++) a[mi] = *(const short8*)&As[wm + mi * 16 + l15][quad * 8];
#pragma unroll
    for (int ni = 0; ni < 4; ni++) b[ni] = *(const short8*)&Bs[wn + ni * 16 + l15][quad * 8];
#pragma unroll
    for (int mi = 0; mi < 4; mi++)
#pragma unroll
      for (int ni = 0; ni < 4; ni++)
        acc[mi][ni] = __builtin_amdgcn_mfma_f32_16x16x32_bf16(a[mi], b[ni], acc[mi][ni], 0, 0, 0);
    __syncthreads();
  }
#pragma unroll
  for (int ni = 0; ni < 4; ni++) {
    int n = j0 + wn + ni * 16 + l15;
    float bias = b2[t * DC + n];
#pragma unroll
    for (int mi = 0; mi < 4; mi++) {
      int mb = wm + mi * 16 + quad * 4;
#pragma unroll
      for (int r = 0; r < 4; r++) {
        int tok = toks[mb + r];
        if (tok >= 0) out[(size_t)tok * DC + n] = acc[mi][ni][r] + bias;
      }
    }
  }
}

extern "C" void kernel_launch(void* const* d_in, const int* in_sizes, int n_in,
                              void* d_out, int out_size, void* d_ws, size_t ws_size,
                              hipStream_t stream) {
  const float* x        = (const float*)d_in[0];
  const float* pe       = (const float*)d_in[1];
  const float* pwp      = (const float*)d_in[2];
  const float* cwp      = (const float*)d_in[3];
  const float* pos_sigs = (const float*)d_in[4];
  const float* csigs    = (const float*)d_in[5];
  const float* W1       = (const float*)d_in[6];
  const float* b1       = (const float*)d_in[7];
  const float* W2       = (const float*)d_in[8];
  const float* b2       = (const float*)d_in[9];
  float* out = (float*)d_out;

  char* ws = (char*)d_ws;
  int* counts = (int*)ws;                       // 32 B
  int* list   = (int*)(ws + 1024);              // 256 KB
  unsigned short* xb = (unsigned short*)(ws + (1 << 20));  // 16 MB @ [1,17)

  hipMemsetAsync(counts, 0, NT * sizeof(int), stream);
  route_kernel<<<NTOK / 4, 256, 0, stream>>>(x, pe, pwp, cwp, pos_sigs, csigs,
                                             counts, list, xb);

  if (ws_size >= (size_t)145 * 1024 * 1024) {
    // fast path: WT @ [17,81) (reused for W1T then W2T), H @ [81,145)
    unsigned short* WT = (unsigned short*)(ws + ((size_t)17 << 20));
    unsigned short* H  = (unsigned short*)(ws + ((size_t)81 << 20));

    transpose_kernel<DC, DH><<<dim3(DH / 64, DC / 64, NT), 256, 0, stream>>>(W1, WT);
    gemm_async_kernel<DC, DH, true><<<dim3(DH / BN, NTOK / BM, NT), 256, 0, stream>>>(
        xb, WT, b1, counts, list, H, nullptr);
    transpose_kernel<DH, DC><<<dim3(DC / 64, DH / 64, NT), 256, 0, stream>>>(W2, WT);
    gemm_async_kernel<DH, DC, false><<<dim3(DC / BN, NTOK / BM, NT), 256, 0, stream>>>(
        H, WT, b2, counts, list, nullptr, out);
  } else {
    // fallback: round-1 structure, 96 MB footprint
    unsigned short* H = (unsigned short*)(ws + ((size_t)32 << 20));
    gemm1_fb<<<dim3(DH / BN, NTOK / BM, NT), 256, 0, stream>>>(xb, W1, b1, counts, list, H);
    gemm2_fb<<<dim3(DC / BN, NTOK / BM, NT), 256, 0, stream>>>(H, W2, b2, counts, list, out);
  }
}